// Round 1
// 3017.089 us; speedup vs baseline: 2.2621x; 2.2621x over previous
//
#include <hip/hip_runtime.h>

constexpr int DIMD  = 512;
constexpr int TOK   = 4096;   // B*S
constexpr int SEQL  = 512;
constexpr int NHEAD = 8;
constexpr int PHD   = 64;
constexpr int FFD   = 2048;
constexpr int NVOC  = 32000;

typedef float f32x4 __attribute__((ext_vector_type(4)));
typedef short bf16x8 __attribute__((ext_vector_type(8)));
typedef unsigned short u16x8 __attribute__((ext_vector_type(8)));
typedef unsigned short u16x4 __attribute__((ext_vector_type(4)));

__device__ __forceinline__ unsigned short f2bf(float f) {
  union { float f; unsigned u; } v; v.f = f;
  unsigned r = v.u + 0x7fffu + ((v.u >> 16) & 1u);  // RNE
  return (unsigned short)(r >> 16);
}

// global -> LDS direct DMA, 16B per lane (dest = wave-uniform base + lane*16)
__device__ __forceinline__ void gl16(const unsigned short* g, unsigned short* l) {
  __builtin_amdgcn_global_load_lds(
      (const __attribute__((address_space(1))) unsigned int*)g,
      (__attribute__((address_space(3))) unsigned int*)l, 16, 0, 0);
}

// ---------------- transpose-convert: dst[N,K] bf16 = src[K,N] f32, per layer z ---
__global__ __launch_bounds__(256)
void convt_kernel(const float* __restrict__ src, unsigned short* __restrict__ dst,
                  int K, int N, size_t srcLS, size_t dstLS) {
  __shared__ float t[32][33];
  const float* s = src + (size_t)blockIdx.z * srcLS;
  unsigned short* d = dst + (size_t)blockIdx.z * dstLS;
  const int n0 = blockIdx.x * 32, k0 = blockIdx.y * 32;
  const int c = threadIdx.x & 31, r = threadIdx.x >> 5;
#pragma unroll
  for (int i = 0; i < 4; ++i)
    t[r + i * 8][c] = s[(size_t)(k0 + r + i * 8) * N + n0 + c];
  __syncthreads();
#pragma unroll
  for (int i = 0; i < 4; ++i)
    d[(size_t)(n0 + r + i * 8) * K + k0 + c] = f2bf(t[c][r + i * 8]);
}

// ---------------- GEMM: C = A[M,K](bf16) @ B[N,K]^T(bf16) (+bias)(+relu) ---------
// m97 structure: BK=64, global_load_lds(16B), XOR-chunk swizzle, 2 barriers/K-step.
// BM=128: 4 waves 2x2, wave tile 64x64 (acc 4x4). BM=64: 4 waves 1x4, 64x32 (4x2).
template<int BM, bool BIAS, bool RELU, bool OBF16>
__global__ __launch_bounds__(256)
void gemm_bt(const unsigned short* __restrict__ A, const unsigned short* __restrict__ B,
             void* __restrict__ Cv, const float* __restrict__ bias,
             int M, int N, int K, int ldc) {
  __shared__ __align__(16) unsigned short AsF[BM * 64];
  __shared__ __align__(16) unsigned short BsF[128 * 64];
  (void)M;
  // XCD-aware bijective swizzle (all grids here are divisible by 8)
  int bx = blockIdx.x, by = blockIdx.y;
  {
    unsigned gx = gridDim.x;
    unsigned nwg = gx * gridDim.y;
    unsigned id = (unsigned)by * gx + (unsigned)bx;
    unsigned cpx = nwg >> 3;
    unsigned ot = (id & 7u) * cpx + (id >> 3);
    bx = (int)(ot % gx); by = (int)(ot / gx);
  }
  const int n0 = bx * 128, m0 = by * BM;
  const int tid = threadIdx.x, lane = tid & 63, wid = tid >> 6;
  const int quad = lane >> 4, l16 = lane & 15;
  constexpr int NJ = (BM == 128) ? 4 : 2;
  const int wm = (BM == 128) ? (wid >> 1) * 64 : 0;
  const int wn = (BM == 128) ? (wid & 1) * 64 : wid * 32;
  const int r8 = lane >> 3, cp = lane & 7;
  const int arow = wid * (BM / 4);   // wave's A staging rows
  const int brow = wid * 32;         // wave's B staging rows
  f32x4 acc[4][NJ] = {};
  for (int k0 = 0; k0 < K; k0 += 64) {
#pragma unroll
    for (int i = 0; i < BM / 32; ++i) {
      int r = arow + i * 8 + r8;
      gl16(A + (size_t)(m0 + r) * K + k0 + ((cp ^ r8) << 3), &AsF[(arow + i * 8) * 64]);
    }
#pragma unroll
    for (int i = 0; i < 4; ++i) {
      int r = brow + i * 8 + r8;
      gl16(B + (size_t)(n0 + r) * K + k0 + ((cp ^ r8) << 3), &BsF[(brow + i * 8) * 64]);
    }
    __syncthreads();
#pragma unroll
    for (int h = 0; h < 2; ++h) {
      const int ch = ((h * 4 + quad) ^ (l16 & 7)) << 3;  // swizzled chunk (8 shorts)
      bf16x8 af[4], bb[NJ];
#pragma unroll
      for (int i = 0; i < 4; ++i)
        af[i] = *reinterpret_cast<const bf16x8*>(&AsF[(wm + i * 16 + l16) * 64 + ch]);
#pragma unroll
      for (int j = 0; j < NJ; ++j)
        bb[j] = *reinterpret_cast<const bf16x8*>(&BsF[(wn + j * 16 + l16) * 64 + ch]);
#pragma unroll
      for (int i = 0; i < 4; ++i)
#pragma unroll
        for (int j = 0; j < NJ; ++j)
          acc[i][j] = __builtin_amdgcn_mfma_f32_16x16x32_bf16(af[i], bb[j], acc[i][j], 0, 0, 0);
    }
    __syncthreads();
  }
#pragma unroll
  for (int i = 0; i < 4; ++i) {
    const int row0 = m0 + wm + i * 16 + quad * 4;
#pragma unroll
    for (int j = 0; j < NJ; ++j) {
      const int col = n0 + wn + j * 16 + l16;
      float bv = 0.f;
      if constexpr (BIAS) bv = bias[col];
#pragma unroll
      for (int r = 0; r < 4; ++r) {
        float v = acc[i][j][r] + bv;
        if constexpr (RELU) v = fmaxf(v, 0.f);
        if constexpr (OBF16)
          ((unsigned short*)Cv)[(size_t)(row0 + r) * ldc + col] = f2bf(v);
        else
          ((float*)Cv)[(size_t)(row0 + r) * ldc + col] = v;
      }
    }
  }
}

// ---------------- Fused flash attention (bf16 in/out) ----------------
// grid (S/64, H, B), 256 thr = 4 waves, each wave 16 q rows; 32 keys/iter.
// Ks [32][64] XOR-swz (key ss&7), Vs [64][32] transposed XOR-swz (key d&3),
// Ps per-wave [16][32] XOR-swz (key row&3).
template<bool CAUSAL>
__global__ __launch_bounds__(256)
void attn_kernel(const unsigned short* __restrict__ Q, const unsigned short* __restrict__ Kk,
                 const unsigned short* __restrict__ V, unsigned short* __restrict__ O,
                 const int* __restrict__ kv_ids, int ldq, int ldkv) {
  __shared__ __align__(16) unsigned short Ks[32 * 64];
  __shared__ __align__(16) unsigned short Vs[64 * 32];
  __shared__ __align__(16) unsigned short Ps[4][16 * 32];
  const int b = blockIdx.z, h = blockIdx.y, q0 = blockIdx.x * 64;
  const int tid = threadIdx.x, wv = tid >> 6, lane = tid & 63;
  const int quad = lane >> 4, l16 = lane & 15;
  const int qrow = q0 + wv * 16 + l16;
  const unsigned short* qp = Q + (size_t)(b * SEQL + qrow) * ldq + h * PHD;
  bf16x8 qf[2];
  qf[0] = *reinterpret_cast<const bf16x8*>(qp + quad * 8);
  qf[1] = *reinterpret_cast<const bf16x8*>(qp + 32 + quad * 8);
  float m_r[4] = {-1e30f, -1e30f, -1e30f, -1e30f};
  float l_r[4] = {0.f, 0.f, 0.f, 0.f};
  f32x4 Oacc[4] = {};
  const int ss = tid >> 3, c8 = tid & 7;
  const unsigned short* kbase = Kk + (size_t)b * SEQL * ldkv + h * PHD;
  const unsigned short* vbase = V + (size_t)b * SEQL * ldkv + h * PHD;
  for (int k0 = 0; k0 < SEQL; k0 += 32) {
    {
      const unsigned short* kp = kbase + (size_t)(k0 + ss) * ldkv + c8 * 8;
      *reinterpret_cast<u16x8*>(&Ks[ss * 64 + ((c8 ^ (ss & 7)) << 3)]) =
          *reinterpret_cast<const u16x8*>(kp);
      u16x8 v8 = *reinterpret_cast<const u16x8*>(vbase + (size_t)(k0 + ss) * ldkv + c8 * 8);
#pragma unroll
      for (int e = 0; e < 8; ++e) {
        int d = c8 * 8 + e;
        Vs[d * 32 + (((ss >> 3) ^ (d & 3)) << 3) + (ss & 7)] = (unsigned short)v8[e];
      }
    }
    __syncthreads();
    f32x4 sc[2];
#pragma unroll
    for (int c = 0; c < 2; ++c) {
      const int kr = (c * 16 + l16) * 64;
      bf16x8 kf0 = *reinterpret_cast<const bf16x8*>(&Ks[kr + ((quad ^ (l16 & 7)) << 3)]);
      bf16x8 kf1 = *reinterpret_cast<const bf16x8*>(&Ks[kr + (((4 + quad) ^ (l16 & 7)) << 3)]);
      f32x4 t = {};
      t = __builtin_amdgcn_mfma_f32_16x16x32_bf16(qf[0], kf0, t, 0, 0, 0);
      t = __builtin_amdgcn_mfma_f32_16x16x32_bf16(qf[1], kf1, t, 0, 0, 0);
      sc[c] = t;
    }
    float alpha[4];
#pragma unroll
    for (int r = 0; r < 4; ++r) {
      const int qg = q0 + wv * 16 + quad * 4 + r;
      float sv0, sv1;
      {
        int col = k0 + l16;
        bool ok = (kv_ids[b * SEQL + col] != 0);
        if (CAUSAL) ok = ok && (col <= qg);
        sv0 = ok ? sc[0][r] * 0.125f : -1e9f;
        col = k0 + 16 + l16;
        ok = (kv_ids[b * SEQL + col] != 0);
        if (CAUSAL) ok = ok && (col <= qg);
        sv1 = ok ? sc[1][r] * 0.125f : -1e9f;
      }
      float mx = fmaxf(sv0, sv1);
#pragma unroll
      for (int off = 1; off < 16; off <<= 1) mx = fmaxf(mx, __shfl_xor(mx, off));
      float mnew = fmaxf(m_r[r], mx);
      alpha[r] = __expf(m_r[r] - mnew);
      float p0 = __expf(sv0 - mnew);
      float p1 = __expf(sv1 - mnew);
      float ps = p0 + p1;
#pragma unroll
      for (int off = 1; off < 16; off <<= 1) ps += __shfl_xor(ps, off);
      l_r[r] = l_r[r] * alpha[r] + ps;
      m_r[r] = mnew;
      const int qr = quad * 4 + r;
      Ps[wv][qr * 32 + (((l16 >> 3) ^ (qr & 3)) << 3) + (l16 & 7)] = f2bf(p0);
      Ps[wv][qr * 32 + (((2 + (l16 >> 3)) ^ (qr & 3)) << 3) + (l16 & 7)] = f2bf(p1);
    }
#pragma unroll
    for (int j = 0; j < 4; ++j)
#pragma unroll
      for (int r = 0; r < 4; ++r) Oacc[j][r] *= alpha[r];
    __builtin_amdgcn_wave_barrier();
    bf16x8 pf = *reinterpret_cast<const bf16x8*>(&Ps[wv][l16 * 32 + ((quad ^ (l16 & 3)) << 3)]);
#pragma unroll
    for (int j = 0; j < 4; ++j) {
      const int d = j * 16 + l16;
      bf16x8 vf = *reinterpret_cast<const bf16x8*>(&Vs[d * 32 + ((quad ^ (d & 3)) << 3)]);
      Oacc[j] = __builtin_amdgcn_mfma_f32_16x16x32_bf16(pf, vf, Oacc[j], 0, 0, 0);
    }
    __syncthreads();
  }
#pragma unroll
  for (int r = 0; r < 4; ++r) {
    const int row = q0 + wv * 16 + quad * 4 + r;
    const float inv = 1.f / l_r[r];
    unsigned short* op = O + (size_t)(b * SEQL + row) * DIMD + h * PHD;
#pragma unroll
    for (int j = 0; j < 4; ++j) op[j * 16 + l16] = f2bf(Oacc[j][r] * inv);
  }
}

// ---------------- out = LayerNorm(x + y)*g + b, fp32 + bf16 copies --------------
__global__ __launch_bounds__(256)
void ln_add_kernel(const float* x, const float* __restrict__ y,
                   const float* __restrict__ g, const float* __restrict__ bb,
                   float* out, unsigned short* out_bf) {
  const int row = blockIdx.x * 4 + (threadIdx.x >> 6);
  const int lane = threadIdx.x & 63;
  const float* xp = x + (size_t)row * DIMD + lane * 8;
  const float* yp = y + (size_t)row * DIMD + lane * 8;
  float4 a0 = *reinterpret_cast<const float4*>(xp);
  float4 a1 = *reinterpret_cast<const float4*>(xp + 4);
  float4 b0 = *reinterpret_cast<const float4*>(yp);
  float4 b1 = *reinterpret_cast<const float4*>(yp + 4);
  float v[8] = {a0.x + b0.x, a0.y + b0.y, a0.z + b0.z, a0.w + b0.w,
                a1.x + b1.x, a1.y + b1.y, a1.z + b1.z, a1.w + b1.w};
  float s = 0.f;
#pragma unroll
  for (int i = 0; i < 8; ++i) s += v[i];
#pragma unroll
  for (int off = 32; off > 0; off >>= 1) s += __shfl_xor(s, off);
  const float mean = s * (1.0f / DIMD);
  float q = 0.f;
#pragma unroll
  for (int i = 0; i < 8; ++i) { float d = v[i] - mean; q += d * d; }
#pragma unroll
  for (int off = 32; off > 0; off >>= 1) q += __shfl_xor(q, off);
  const float rs = rsqrtf(q * (1.0f / DIMD) + 1e-5f);
  const float* gp = g + lane * 8;
  const float* bp = bb + lane * 8;
  float o[8];
#pragma unroll
  for (int i = 0; i < 8; ++i) o[i] = (v[i] - mean) * rs * gp[i] + bp[i];
  float* op = out + (size_t)row * DIMD + lane * 8;
  float4 w0 = {o[0], o[1], o[2], o[3]};
  float4 w1 = {o[4], o[5], o[6], o[7]};
  *reinterpret_cast<float4*>(op) = w0;
  *reinterpret_cast<float4*>(op + 4) = w1;
  unsigned short* obp = out_bf + (size_t)row * DIMD + lane * 8;
  u16x4 h0 = {f2bf(o[0]), f2bf(o[1]), f2bf(o[2]), f2bf(o[3])};
  u16x4 h1 = {f2bf(o[4]), f2bf(o[5]), f2bf(o[6]), f2bf(o[7])};
  *reinterpret_cast<u16x4*>(obp) = h0;
  *reinterpret_cast<u16x4*>(obp + 4) = h1;
}

// ---------------- x = emb[id]*sqrt(D) + pe, fp32 + bf16 copies ----------------
__global__ __launch_bounds__(256)
void embed_kernel(const int* __restrict__ ids, const float* __restrict__ emb,
                  float* __restrict__ out, unsigned short* __restrict__ out_bf) {
  const int t = blockIdx.x;
  const int s = t & (SEQL - 1);
  const int id = ids[t];
  const int d = threadIdx.x * 2;
  float2 e = *reinterpret_cast<const float2*>(emb + (size_t)id * DIMD + d);
  const float c = -0.017988946039015984f;  // -ln(10000)/512
  const float div = expf((float)d * c);
  const float ang = (float)s * div;
  const float sq = 22.627416997969522f;    // sqrt(512)
  float2 o;
  o.x = e.x * sq + sinf(ang);
  o.y = e.y * sq + cosf(ang);
  *reinterpret_cast<float2*>(out + (size_t)t * DIMD + d) = o;
  unsigned pk = (unsigned)f2bf(o.x) | ((unsigned)f2bf(o.y) << 16);
  *reinterpret_cast<unsigned*>(out_bf + (size_t)t * DIMD + d) = pk;
}

extern "C" void kernel_launch(void* const* d_in, const int* in_sizes, int n_in,
                              void* d_out, int out_size, void* d_ws, size_t ws_size,
                              hipStream_t stream) {
  (void)in_sizes; (void)n_in; (void)out_size;
  typedef unsigned short us;
  const int*   input   = (const int*)d_in[0];
  const int*   target  = (const int*)d_in[1];
  const float* emb     = (const float*)d_in[2];
  const float* out_w   = (const float*)d_in[3];
  const float* out_b   = (const float*)d_in[4];
  const float* e_wq    = (const float*)d_in[5];
  const float* e_wk    = (const float*)d_in[6];
  const float* e_wv    = (const float*)d_in[7];
  const float* e_wo    = (const float*)d_in[8];
  const float* e_ff1_w = (const float*)d_in[9];
  const float* e_ff1_b = (const float*)d_in[10];
  const float* e_ff2_w = (const float*)d_in[11];
  const float* e_ff2_b = (const float*)d_in[12];
  const float* e_ln1_g = (const float*)d_in[13];
  const float* e_ln1_b = (const float*)d_in[14];
  const float* e_ln2_g = (const float*)d_in[15];
  const float* e_ln2_b = (const float*)d_in[16];
  const float* d_swq   = (const float*)d_in[17];
  const float* d_swk   = (const float*)d_in[18];
  const float* d_swv   = (const float*)d_in[19];
  const float* d_swo   = (const float*)d_in[20];
  const float* d_cwq   = (const float*)d_in[21];
  const float* d_cwk   = (const float*)d_in[22];
  const float* d_cwv   = (const float*)d_in[23];
  const float* d_cwo   = (const float*)d_in[24];
  const float* d_ff1_w = (const float*)d_in[25];
  const float* d_ff1_b = (const float*)d_in[26];
  const float* d_ff2_w = (const float*)d_in[27];
  const float* d_ff2_b = (const float*)d_in[28];
  const float* d_ln1_g = (const float*)d_in[29];
  const float* d_ln1_b = (const float*)d_in[30];
  const float* d_ln2_g = (const float*)d_in[31];
  const float* d_ln2_b = (const float*)d_in[32];
  const float* d_ln3_g = (const float*)d_in[33];
  const float* d_ln3_b = (const float*)d_in[34];

  constexpr size_t WDD  = (size_t)512 * 512;      // 262144 elems
  constexpr size_t WQKV = (size_t)1536 * 512;     // fused qkv per layer
  constexpr size_t WFF  = (size_t)2048 * 512;
  char* base = (char*)d_ws;
  float* xe    = (float*)(base + 0);               // 8 MB
  float* xd    = (float*)(base + 8388608);         // 8 MB
  float* yb    = (float*)(base + 16777216);        // 8 MB
  us*    xe_bf = (us*)(base + 25165824);           // 4 MB
  us*    xd_bf = (us*)(base + 29360128);           // 4 MB
  us*    qkv_bf = (us*)(base + 33554432);          // 12 MB  [TOK,1536]
  us*    ctx_bf = (us*)(base + 46137344);          // 4 MB   [TOK,512]
  us*    ff_bf  = qkv_bf;                          // 16 MB union (qkv+ctx dead then)
  char*  wreg   = base + 50331648;                 // weights region / scratch
  const bool full = ws_size >= (size_t)50331648 + 120848384;
  us* scr = (us*)wreg;  // compact-mode rotating scratch (needs <= 32.8 MB)

  us* p = (us*)wreg;
  us* ewqkv = p; p += 6 * WQKV;
  us* ewo   = p; p += 6 * WDD;
  us* eff1  = p; p += 6 * WFF;
  us* eff2  = p; p += 6 * WFF;
  us* dsqkv = p; p += 6 * WQKV;
  us* dswo  = p; p += 6 * WDD;
  us* dcq   = p; p += 6 * WDD;
  us* dckv  = p; p += 6 * 2 * WDD;
  us* dcwo  = p; p += 6 * WDD;
  us* dff1  = p; p += 6 * WFF;
  us* dff2  = p; p += 6 * WFF;
  us* owT   = p;

  dim3 blk(256);
  auto cvt = [&](const float* src, us* dst, int K, int N, int L, size_t dstLS) {
    dim3 g(N / 32, K / 32, L);
    convt_kernel<<<g, blk, 0, stream>>>(src, dst, K, N, (size_t)K * (size_t)N, dstLS);
  };

  if (full) {
    cvt(e_wq, ewqkv, 512, 512, 6, WQKV);
    cvt(e_wk, ewqkv + WDD, 512, 512, 6, WQKV);
    cvt(e_wv, ewqkv + 2 * WDD, 512, 512, 6, WQKV);
    cvt(e_wo, ewo, 512, 512, 6, WDD);
    cvt(e_ff1_w, eff1, 512, 2048, 6, WFF);
    cvt(e_ff2_w, eff2, 2048, 512, 6, WFF);
    cvt(d_swq, dsqkv, 512, 512, 6, WQKV);
    cvt(d_swk, dsqkv + WDD, 512, 512, 6, WQKV);
    cvt(d_swv, dsqkv + 2 * WDD, 512, 512, 6, WQKV);
    cvt(d_swo, dswo, 512, 512, 6, WDD);
    cvt(d_cwq, dcq, 512, 512, 6, WDD);
    cvt(d_cwk, dckv, 512, 512, 6, 2 * WDD);
    cvt(d_cwv, dckv + WDD, 512, 512, 6, 2 * WDD);
    cvt(d_cwo, dcwo, 512, 512, 6, WDD);
    cvt(d_ff1_w, dff1, 512, 2048, 6, WFF);
    cvt(d_ff2_w, dff2, 2048, 512, 6, WFF);
    cvt(out_w, owT, 512, NVOC, 1, 0);
  }

  dim3 ag(SEQL / 64, NHEAD, 8);
  embed_kernel<<<TOK, blk, 0, stream>>>(input, emb, xe, xe_bf);
  embed_kernel<<<TOK, blk, 0, stream>>>(target, emb, xd, xd_bf);

  for (int l = 0; l < 6; ++l) {
    const us* Wqkv; const us* Wo; const us* W1; const us* W2;
    if (full) {
      Wqkv = ewqkv + (size_t)l * WQKV; Wo = ewo + (size_t)l * WDD;
      W1 = eff1 + (size_t)l * WFF;     W2 = eff2 + (size_t)l * WFF;
    } else {
      cvt(e_wq + (size_t)l * WDD, scr, 512, 512, 1, 0);
      cvt(e_wk + (size_t)l * WDD, scr + WDD, 512, 512, 1, 0);
      cvt(e_wv + (size_t)l * WDD, scr + 2 * WDD, 512, 512, 1, 0);
      Wqkv = scr; Wo = scr; W1 = scr; W2 = scr;
    }
    gemm_bt<128, false, false, true><<<dim3(12, 32), blk, 0, stream>>>(
        xe_bf, Wqkv, qkv_bf, nullptr, TOK, 1536, 512, 1536);
    attn_kernel<false><<<ag, blk, 0, stream>>>(
        qkv_bf, qkv_bf + 512, qkv_bf + 1024, ctx_bf, input, 1536, 1536);
    if (!full) cvt(e_wo + (size_t)l * WDD, scr, 512, 512, 1, 0);
    gemm_bt<64, false, false, false><<<dim3(4, 64), blk, 0, stream>>>(
        ctx_bf, Wo, yb, nullptr, TOK, 512, 512, 512);
    ln_add_kernel<<<TOK / 4, blk, 0, stream>>>(
        xe, yb, e_ln1_g + l * DIMD, e_ln1_b + l * DIMD, xe, xe_bf);
    if (!full) cvt(e_ff1_w + (size_t)l * WFF, scr, 512, 2048, 1, 0);
    gemm_bt<128, true, true, true><<<dim3(16, 32), blk, 0, stream>>>(
        xe_bf, W1, ff_bf, e_ff1_b + l * FFD, TOK, FFD, 512, FFD);
    if (!full) cvt(e_ff2_w + (size_t)l * WFF, scr, 2048, 512, 1, 0);
    gemm_bt<64, true, false, false><<<dim3(4, 64), blk, 0, stream>>>(
        ff_bf, W2, yb, e_ff2_b + l * DIMD, TOK, 512, FFD, 512);
    ln_add_kernel<<<TOK / 4, blk, 0, stream>>>(
        xe, yb, e_ln2_g + l * DIMD, e_ln2_b + l * DIMD, xe, xe_bf);
  }

  for (int l = 0; l < 6; ++l) {
    const us* Wsqkv; const us* Wso; const us* Wcq; const us* Wckv; const us* Wco;
    const us* W1; const us* W2;
    if (full) {
      Wsqkv = dsqkv + (size_t)l * WQKV; Wso = dswo + (size_t)l * WDD;
      Wcq = dcq + (size_t)l * WDD;      Wckv = dckv + (size_t)l * 2 * WDD;
      Wco = dcwo + (size_t)l * WDD;
      W1 = dff1 + (size_t)l * WFF;      W2 = dff2 + (size_t)l * WFF;
    } else {
      Wsqkv = Wso = Wcq = Wckv = Wco = W1 = W2 = scr;
    }
    // masked self-attention
    if (!full) {
      cvt(d_swq + (size_t)l * WDD, scr, 512, 512, 1, 0);
      cvt(d_swk + (size_t)l * WDD, scr + WDD, 512, 512, 1, 0);
      cvt(d_swv + (size_t)l * WDD, scr + 2 * WDD, 512, 512, 1, 0);
    }
    gemm_bt<128, false, false, true><<<dim3(12, 32), blk, 0, stream>>>(
        xd_bf, Wsqkv, qkv_bf, nullptr, TOK, 1536, 512, 1536);
    attn_kernel<true><<<ag, blk, 0, stream>>>(
        qkv_bf, qkv_bf + 512, qkv_bf + 1024, ctx_bf, target, 1536, 1536);
    if (!full) cvt(d_swo + (size_t)l * WDD, scr, 512, 512, 1, 0);
    gemm_bt<64, false, false, false><<<dim3(4, 64), blk, 0, stream>>>(
        ctx_bf, Wso, yb, nullptr, TOK, 512, 512, 512);
    ln_add_kernel<<<TOK / 4, blk, 0, stream>>>(
        xd, yb, d_ln1_g + l * DIMD, d_ln1_b + l * DIMD, xd, xd_bf);
    // cross-attention (KV from encoder output)
    if (!full) cvt(d_cwq + (size_t)l * WDD, scr, 512, 512, 1, 0);
    gemm_bt<64, false, false, true><<<dim3(4, 64), blk, 0, stream>>>(
        xd_bf, Wcq, qkv_bf, nullptr, TOK, 512, 512, 1536);
    if (!full) {
      cvt(d_cwk + (size_t)l * WDD, scr, 512, 512, 1, 0);
      cvt(d_cwv + (size_t)l * WDD, scr + WDD, 512, 512, 1, 0);
    }
    gemm_bt<128, false, false, true><<<dim3(8, 32), blk, 0, stream>>>(
        xe_bf, Wckv, qkv_bf + 512, nullptr, TOK, 1024, 512, 1536);
    attn_kernel<false><<<ag, blk, 0, stream>>>(
        qkv_bf, qkv_bf + 512, qkv_bf + 1024, ctx_bf, input, 1536, 1536);
    if (!full) cvt(d_cwo + (size_t)l * WDD, scr, 512, 512, 1, 0);
    gemm_bt<64, false, false, false><<<dim3(4, 64), blk, 0, stream>>>(
        ctx_bf, Wco, yb, nullptr, TOK, 512, 512, 512);
    ln_add_kernel<<<TOK / 4, blk, 0, stream>>>(
        xd, yb, d_ln2_g + l * DIMD, d_ln2_b + l * DIMD, xd, xd_bf);
    // FF
    if (!full) cvt(d_ff1_w + (size_t)l * WFF, scr, 512, 2048, 1, 0);
    gemm_bt<128, true, true, true><<<dim3(16, 32), blk, 0, stream>>>(
        xd_bf, W1, ff_bf, d_ff1_b + l * FFD, TOK, FFD, 512, FFD);
    if (!full) cvt(d_ff2_w + (size_t)l * WFF, scr, 2048, 512, 1, 0);
    gemm_bt<64, true, false, false><<<dim3(4, 64), blk, 0, stream>>>(
        ff_bf, W2, yb, d_ff2_b + l * DIMD, TOK, 512, FFD, 512);
    ln_add_kernel<<<TOK / 4, blk, 0, stream>>>(
        xd, yb, d_ln3_g + l * DIMD, d_ln3_b + l * DIMD, xd, xd_bf);
  }

  // final vocab projection straight into d_out
  const us* Wv = owT;
  if (!full) { cvt(out_w, scr, 512, NVOC, 1, 0); Wv = scr; }
  gemm_bt<128, true, false, false><<<dim3(NVOC / 128, 32), blk, 0, stream>>>(
      xd_bf, Wv, (float*)d_out, out_b, TOK, NVOC, 512, NVOC);
}